// Round 12
// baseline (439.575 us; speedup 1.0000x reference)
//
#include <hip/hip_runtime.h>

// MessagePassingNet on MI355X — Round 12: bucket scatter replaces counting sort.
//   * cnt/bucket (cap 16/atom, Poisson(8) => ~900 overflow edges) kills
//     hist+scan chain AND new_states zeroing AND all edge-kernel atomics.
//   * edge_v8: wave = 2 consecutive atoms x 16 slots; dst reads wave-uniform;
//     reduction = bounded column sums, plain stores.
//   * overflow fixup: tiny fp32 kernel, atomicAdd (runs after edge stores).
//   * 5 dispatches: k0(init+pack) -> k1(scatter||atom_pre) -> edge -> ovf -> atom.

constexpr int N_ATOMS = 131072;
constexpr int N_EDGES = 1048576;
constexpr int DD      = 64;
constexpr int OUTD    = 16;
constexpr int SH      = 72;     // halfword row stride for hi/lo LDS tiles
constexpr int SY      = 68;     // float row stride for atom_pre staging
constexpr int BCAP    = 16;     // bucket capacity per atom
constexpr int OVF_CAP = 262144; // overflow list capacity (>>290x expected ~900)

typedef __bf16 bf16x8 __attribute__((ext_vector_type(8)));
typedef float  f32x4  __attribute__((ext_vector_type(4)));
typedef unsigned short u16x8 __attribute__((ext_vector_type(8)));

#define DEV_INLINE __device__ __forceinline__

DEV_INLINE float relu(float x) { return x > 0.f ? x : 0.f; }

DEV_INLINE unsigned short bfbits(float x) {
  __bf16 h = (__bf16)x;
  return __builtin_bit_cast(unsigned short, h);
}
DEV_INLINE float bfval(unsigned short u) {
  unsigned int v = ((unsigned int)u) << 16;
  return __builtin_bit_cast(float, v);
}
DEV_INLINE f32x4 mfma16(bf16x8 a, bf16x8 b, f32x4 c) {
  return __builtin_amdgcn_mfma_f32_16x16x32_bf16(a, b, c, 0, 0, 0);
}
DEV_INLINE bf16x8 ldfrag(const unsigned short* p) { return *(const bf16x8*)p; }

DEV_INLINE float4 ldnt(const float4* p) {
  f32x4 v = __builtin_nontemporal_load((const f32x4*)p);
  return make_float4(v.x, v.y, v.z, v.w);
}

DEV_INLINE void mk_frag(float4 a0, float4 a1, bf16x8& fh, bf16x8& fl) {
  const float v[8] = {a0.x, a0.y, a0.z, a0.w, a1.x, a1.y, a1.z, a1.w};
  u16x8 hh, ll;
#pragma unroll
  for (int i = 0; i < 8; ++i) {
    unsigned short h = bfbits(v[i]);
    hh[i] = h;
    ll[i] = bfbits(v[i] - bfval(h));
  }
  fh = __builtin_bit_cast(bf16x8, hh);
  fl = __builtin_bit_cast(bf16x8, ll);
}

// ===========================================================================
// k0: blocks [0,128) zero cnt (int4/thread) | b==128 zero ovf_cnt |
//     blocks [129,141) weight pack. Sections: 0=W0d 1=W0s 2=W1 3=W2 4=FC1 5=FC2.
// fo(sec,j,s,l) = sec*4096 + ((j*2+s)*64 + l)*8
// ===========================================================================
__global__ __launch_bounds__(256)
void k0_init_pack(const float* __restrict__ w0, const float* __restrict__ w1,
                  const float* __restrict__ w2, const float* __restrict__ f1,
                  const float* __restrict__ f2,
                  int* __restrict__ cnt, int* __restrict__ ovf_cnt,
                  unsigned short* __restrict__ whi, unsigned short* __restrict__ wlo)
{
  const int t = threadIdx.x, b = blockIdx.x;
  if (b < 128) {
    ((int4*)cnt)[b * 256 + t] = make_int4(0, 0, 0, 0);   // 128*256 int4 = 131072 ints
  } else if (b == 128) {
    if (t == 0) *ovf_cnt = 0;
  } else {
    int tid = (b - 129) * 256 + t;                       // 0..3071
    int sec = tid >> 9, rel = tid & 511;
    const float* w; int rowoff = 0;
    switch (sec) {
      case 0: w = w0; rowoff = 0;  break;
      case 1: w = w0; rowoff = 64; break;
      case 2: w = w1; break;
      case 3: w = w2; break;
      case 4: w = f1; break;
      default: w = f2; break;
    }
    const int tile = rel >> 6, lane = rel & 63;
    const int j = tile >> 1, s = tile & 1;
    const int n  = j * 16 + (lane & 15);
    const int kb = s * 32 + (lane >> 4) * 8;
    const int out = sec * 4096 + (tile * 64 + lane) * 8;
#pragma unroll
    for (int i = 0; i < 8; ++i) {
      float v = w[(rowoff + kb + i) * 64 + n];
      unsigned short h = bfbits(v);
      whi[out + i] = h;
      wlo[out + i] = bfbits(v - bfval(h));
    }
  }
}

// ===========================================================================
// k1: blocks [0,4096) bucket-scatter | [4096,6144) atom_pre.
// ===========================================================================
__global__ __launch_bounds__(256, 4)
void k1_scatter_pre(const float* __restrict__ atom_states,
                    const int* __restrict__ edge_src,
                    const int* __restrict__ edge_dst,
                    int* __restrict__ cnt,
                    int* __restrict__ bucket,
                    int2* __restrict__ ovf, int* __restrict__ ovf_cnt,
                    const unsigned short* __restrict__ whi,
                    const unsigned short* __restrict__ wlo,
                    const float* __restrict__ b0,
                    float* __restrict__ Yd, float* __restrict__ Ys)
{
  __shared__ float Ystage[4][16 * SY];

  const int t = threadIdx.x, b = blockIdx.x;

  if (b < 4096) {                        // bucket scatter
    int i = b * 256 + t;
    int d = edge_dst[i];
    int pos = atomicAdd(&cnt[d], 1);
    if (pos < BCAP) {
      bucket[d * BCAP + pos] = edge_src[i];
    } else {
      int op = atomicAdd(ovf_cnt, 1);
      if (op < OVF_CAP) ovf[op] = make_int2(d, edge_src[i]);
    }
    return;
  }

  // ---- atom_pre: Yd = X*W0d + b0, Ys = X*W0s (register A-frags, LDS-staged
  // coalesced stores)
  const int a0 = (b - 4096) * 64;
  const int l  = t & 63;
  const int w  = t >> 6;
  const int fi = (l >> 4) * 2;
  const int cc = l & 15;
  const int arow = a0 + w * 16 + (l & 15);
  float* st = Ystage[w];

  bf16x8 xh[2], xl[2];
  {
    const float4* px = (const float4*)(atom_states + (size_t)arow * DD);
#pragma unroll
    for (int s = 0; s < 2; ++s) {
      float4 x0 = px[s * 8 + fi], x1 = px[s * 8 + fi + 1];
      mk_frag(x0, x1, xh[s], xl[s]);
    }
  }

#pragma unroll
  for (int side = 0; side < 2; ++side) {
    f32x4 acc[4];
#pragma unroll
    for (int j = 0; j < 4; ++j) acc[j] = (f32x4){0.f, 0.f, 0.f, 0.f};
#pragma unroll
    for (int s = 0; s < 2; ++s) {
#pragma unroll
      for (int j = 0; j < 4; ++j) {
        const int fo = side * 4096 + ((j * 2 + s) * 64 + l) * 8;
        bf16x8 bh = ldfrag(whi + fo);
        bf16x8 bl = ldfrag(wlo + fo);
        acc[j] = mfma16(xl[s], bh, acc[j]);
        acc[j] = mfma16(xh[s], bl, acc[j]);
        acc[j] = mfma16(xh[s], bh, acc[j]);
      }
    }
#pragma unroll
    for (int j = 0; j < 4; ++j) {
      const int   c  = j * 16 + cc;
      const float bb = side ? 0.f : b0[c];
#pragma unroll
      for (int i = 0; i < 4; ++i) {
        const int r = (l >> 4) * 4 + i;
        st[r * SY + c] = acc[j][i] + bb;
      }
    }
    {
      float* Y = side ? Ys : Yd;
      const int rr = l >> 2;
      const int c0 = (l & 3) * 16;
      float4* dst = (float4*)(Y + (size_t)(a0 + w * 16 + rr) * DD + c0);
      const float4* src = (const float4*)&st[rr * SY + c0];
#pragma unroll
      for (int f = 0; f < 4; ++f) dst[f] = src[f];
    }
  }
}

// ===========================================================================
// edge_kernel_v8: wave = 2 consecutive atoms x 16 bucket slots = 32 rows.
// dst-side Yd reads wave-uniform; src from bucket (invalid slots clamp to
// row 0, masked out by the bounded reduction). 2 A-tiles share B-fragments.
// Plain coalesced stores, ZERO atomics. LDS 36.9 KB/WG.
// ===========================================================================
__global__ __launch_bounds__(256, 4)
void edge_kernel_v8(const float* __restrict__ Yd,
                    const float* __restrict__ Ys,
                    const int* __restrict__ bucket,
                    const int* __restrict__ cnt,
                    const unsigned short* __restrict__ whi,
                    const unsigned short* __restrict__ wlo,
                    const float* __restrict__ b1,
                    const float* __restrict__ b2,
                    float* __restrict__ new_states)
{
  __shared__ __align__(16) unsigned short H2[4][2 * 32 * SH];  // h2 hi|lo; msg aliases

  const int t = threadIdx.x;
  const int w = t >> 6;
  const int l = t & 63;
  const int aw = (blockIdx.x * 4 + w) * 2;   // this wave's 2 atoms

  unsigned short* h2 = H2[w];
  float* msg = (float*)H2[w];

  const int c0 = min(cnt[aw], BCAP);         // wave-uniform -> scalar loads
  const int c1 = min(cnt[aw + 1], BCAP);

  // ---- src per row: lanes 0..31 = (atom l>>4, slot l&15)
  int srcr = 0;
  if (l < 32) {
    const int slot = l & 15;
    const int cap  = (l < 16) ? c0 : c1;
    if (slot < cap) srcr = bucket[(aw + (l >> 4)) * BCAP + slot];
  }

  const int m  = l & 15;
  const int fi = (l >> 4) * 2;
  const int cc = l & 15;

  // ---- gather h1 = relu(Yd[atom] + Ys[src]) into A-fragments, 2 tiles
  bf16x8 a1h[2][2], a1l[2][2];
#pragma unroll
  for (int tile = 0; tile < 2; ++tile) {
    const int sm = __shfl(srcr, tile * 16 + m);
    const float4* pd = (const float4*)(Yd + (size_t)(aw + tile) * DD);  // uniform
    const float4* ps = (const float4*)(Ys + (size_t)sm * DD);
#pragma unroll
    for (int s2 = 0; s2 < 2; ++s2) {
      float4 x0 = pd[s2 * 8 + fi], x1 = pd[s2 * 8 + fi + 1];
      float4 y0 = ldnt(ps + s2 * 8 + fi), y1 = ldnt(ps + s2 * 8 + fi + 1);
      float4 r0 = make_float4(relu(x0.x + y0.x), relu(x0.y + y0.y),
                              relu(x0.z + y0.z), relu(x0.w + y0.w));
      float4 r1 = make_float4(relu(x1.x + y1.x), relu(x1.y + y1.y),
                              relu(x1.z + y1.z), relu(x1.w + y1.w));
      mk_frag(r0, r1, a1h[tile][s2], a1l[tile][s2]);
    }
  }

  f32x4 acc[2][4];

  // ---- layer 1 (A = regs, B sec 2): B-fragments shared by both tiles
#pragma unroll
  for (int tile = 0; tile < 2; ++tile)
#pragma unroll
    for (int j = 0; j < 4; ++j) acc[tile][j] = (f32x4){0.f, 0.f, 0.f, 0.f};
#pragma unroll
  for (int s2 = 0; s2 < 2; ++s2) {
#pragma unroll
    for (int j = 0; j < 4; ++j) {
      const int fo = 2 * 4096 + ((j * 2 + s2) * 64 + l) * 8;
      bf16x8 bh = ldfrag(whi + fo);
      bf16x8 bl = ldfrag(wlo + fo);
#pragma unroll
      for (int tile = 0; tile < 2; ++tile) {
        acc[tile][j] = mfma16(a1l[tile][s2], bh, acc[tile][j]);
        acc[tile][j] = mfma16(a1h[tile][s2], bl, acc[tile][j]);
        acc[tile][j] = mfma16(a1h[tile][s2], bh, acc[tile][j]);
      }
    }
  }
#pragma unroll
  for (int tile = 0; tile < 2; ++tile) {
#pragma unroll
    for (int j = 0; j < 4; ++j) {
      const int   c  = j * 16 + cc;
      const float bb = b1[c];
#pragma unroll
      for (int i = 0; i < 4; ++i) {
        const int r = tile * 16 + (l >> 4) * 4 + i;
        float v = relu(acc[tile][j][i] + bb);
        unsigned short hi = bfbits(v);
        h2[r * SH + c] = hi;
        h2[32 * SH + r * SH + c] = bfbits(v - bfval(hi));
      }
    }
  }

  // ---- layer 2 (A = h2 LDS, B sec 3) -> msg fp32 (aliases h2; same-wave order)
#pragma unroll
  for (int tile = 0; tile < 2; ++tile)
#pragma unroll
    for (int j = 0; j < 4; ++j) acc[tile][j] = (f32x4){0.f, 0.f, 0.f, 0.f};
  const int kq = (l >> 4) * 8;
#pragma unroll
  for (int s2 = 0; s2 < 2; ++s2) {
    bf16x8 ah[2], al[2];
#pragma unroll
    for (int tile = 0; tile < 2; ++tile) {
      const int mrow = tile * 16 + m;
      ah[tile] = ldfrag(&h2[mrow * SH + s2 * 32 + kq]);
      al[tile] = ldfrag(&h2[32 * SH + mrow * SH + s2 * 32 + kq]);
    }
#pragma unroll
    for (int j = 0; j < 4; ++j) {
      const int fo = 3 * 4096 + ((j * 2 + s2) * 64 + l) * 8;
      bf16x8 bh = ldfrag(whi + fo);
      bf16x8 bl = ldfrag(wlo + fo);
#pragma unroll
      for (int tile = 0; tile < 2; ++tile) {
        acc[tile][j] = mfma16(al[tile], bh, acc[tile][j]);
        acc[tile][j] = mfma16(ah[tile], bl, acc[tile][j]);
        acc[tile][j] = mfma16(ah[tile], bh, acc[tile][j]);
      }
    }
  }
#pragma unroll
  for (int tile = 0; tile < 2; ++tile) {
#pragma unroll
    for (int j = 0; j < 4; ++j) {
      const int   c  = j * 16 + cc;
      const float bb = b2[c];
#pragma unroll
      for (int i = 0; i < 4; ++i) {
        const int r = tile * 16 + (l >> 4) * 4 + i;
        msg[r * SH + c] = relu(acc[tile][j][i] + bb);
      }
    }
  }

  // ---- reduction: lane owns column l; bounded sums; plain stores (no atomics,
  // no zero-init needed — every atom written by exactly one wave; overflow
  // edges added later by ovf_kernel's atomicAdd).
  {
    float s0 = 0.f, s1 = 0.f;
    for (int r = 0; r < c0; ++r) s0 += msg[r * SH + l];
    for (int r = 0; r < c1; ++r) s1 += msg[(16 + r) * SH + l];
    new_states[(size_t)aw * DD + l]       = s0;
    new_states[(size_t)(aw + 1) * DD + l] = s1;
  }
}

// ===========================================================================
// ovf_kernel: fp32 message MLP for overflow edges (expected ~900), one wave
// per edge, atomicAdd on top of edge_v8's stores.
// ===========================================================================
__global__ __launch_bounds__(256, 4)
void ovf_kernel(const float* __restrict__ Yd, const float* __restrict__ Ys,
                const float* __restrict__ w1, const float* __restrict__ b1,
                const float* __restrict__ w2, const float* __restrict__ b2,
                const int2* __restrict__ ovf, const int* __restrict__ ovf_cnt,
                float* __restrict__ new_states)
{
  __shared__ float hb[4][64];
  const int t = threadIdx.x;
  const int w = t >> 6;
  const int l = t & 63;
  const int wid = blockIdx.x * 4 + w;
  const int NW  = gridDim.x * 4;

  const int n = min(*ovf_cnt, OVF_CAP);
  for (int e = wid; e < n; e += NW) {
    int2 ds = ovf[e];
    float h1 = relu(Yd[(size_t)ds.x * DD + l] + Ys[(size_t)ds.y * DD + l]);
    hb[w][l] = h1;                       // same-wave LDS, in-order
    float acc = 0.f;
#pragma unroll 8
    for (int k = 0; k < 64; ++k) acc += hb[w][k] * w1[k * 64 + l];
    float h2 = relu(acc + b1[l]);
    hb[w][l] = h2;
    acc = 0.f;
#pragma unroll 8
    for (int k = 0; k < 64; ++k) acc += hb[w][k] * w2[k * 64 + l];
    atomicAdd(&new_states[(size_t)ds.x * DD + l], relu(acc + b2[l]));
  }
}

// ===========================================================================
// atom_kernel_v2 (proven): readout MFMA + fp32 out + mol sum.
// ===========================================================================
__global__ __launch_bounds__(256, 4)
void atom_kernel_v2(const float* __restrict__ ns,
                    const unsigned short* __restrict__ whi,
                    const unsigned short* __restrict__ wlo,
                    const float* __restrict__ f1b,
                    const float* __restrict__ f2b,
                    const float* __restrict__ wo,
                    const float* __restrict__ bo,
                    float* __restrict__ out)
{
  __shared__ __align__(16) unsigned short Xb[2 * 64 * SH];
  __shared__ __align__(16) unsigned short Hb[2 * 64 * SH];
  unsigned short* Xh = Xb;
  unsigned short* Xl = Xb + 64 * SH;
  unsigned short* Hh = Hb;
  unsigned short* Hl = Hb + 64 * SH;
  float* h2f = (float*)Xb;
  float* oS  = (float*)Hb;

  const int t  = threadIdx.x;
  const int a0 = blockIdx.x * 64;

  {
    const int r  = t >> 2;
    const int k0 = (t & 3) * 16;
    const float4* s4 = (const float4*)(ns + (size_t)(a0 + r) * DD + k0);
#pragma unroll
    for (int f = 0; f < 4; ++f) {
      float4 v = s4[f];
      ushort4 h, lo;
      h.x = bfbits(v.x); lo.x = bfbits(v.x - bfval(h.x));
      h.y = bfbits(v.y); lo.y = bfbits(v.y - bfval(h.y));
      h.z = bfbits(v.z); lo.z = bfbits(v.z - bfval(h.z));
      h.w = bfbits(v.w); lo.w = bfbits(v.w - bfval(h.w));
      *(ushort4*)&Xh[r * SH + k0 + f * 4] = h;
      *(ushort4*)&Xl[r * SH + k0 + f * 4] = lo;
    }
  }

  const int l    = t & 63;
  const int w    = t >> 6;
  const int mrow = w * 16 + (l & 15);
  const int kq   = (l >> 4) * 8;
  const int cc   = l & 15;

  f32x4 acc[4];

#pragma unroll
  for (int j = 0; j < 4; ++j) acc[j] = (f32x4){0.f, 0.f, 0.f, 0.f};
#pragma unroll
  for (int s = 0; s < 2; ++s) {
    bf16x8 ah = ldfrag(&Xh[mrow * SH + s * 32 + kq]);
    bf16x8 al = ldfrag(&Xl[mrow * SH + s * 32 + kq]);
#pragma unroll
    for (int j = 0; j < 4; ++j) {
      const int fo = 4 * 4096 + ((j * 2 + s) * 64 + l) * 8;
      bf16x8 bh = ldfrag(whi + fo);
      bf16x8 bl = ldfrag(wlo + fo);
      acc[j] = mfma16(al, bh, acc[j]);
      acc[j] = mfma16(ah, bl, acc[j]);
      acc[j] = mfma16(ah, bh, acc[j]);
    }
  }
#pragma unroll
  for (int j = 0; j < 4; ++j) {
    const int   c  = j * 16 + cc;
    const float bb = f1b[c];
#pragma unroll
    for (int i = 0; i < 4; ++i) {
      const int r = w * 16 + (l >> 4) * 4 + i;
      float v = relu(acc[j][i] + bb);
      unsigned short hi = bfbits(v);
      Hh[r * SH + c] = hi;
      Hl[r * SH + c] = bfbits(v - bfval(hi));
    }
  }
  __syncthreads();

#pragma unroll
  for (int j = 0; j < 4; ++j) acc[j] = (f32x4){0.f, 0.f, 0.f, 0.f};
#pragma unroll
  for (int s = 0; s < 2; ++s) {
    bf16x8 ah = ldfrag(&Hh[mrow * SH + s * 32 + kq]);
    bf16x8 al = ldfrag(&Hl[mrow * SH + s * 32 + kq]);
#pragma unroll
    for (int j = 0; j < 4; ++j) {
      const int fo = 5 * 4096 + ((j * 2 + s) * 64 + l) * 8;
      bf16x8 bh = ldfrag(whi + fo);
      bf16x8 bl = ldfrag(wlo + fo);
      acc[j] = mfma16(al, bh, acc[j]);
      acc[j] = mfma16(ah, bl, acc[j]);
      acc[j] = mfma16(ah, bh, acc[j]);
    }
  }
#pragma unroll
  for (int j = 0; j < 4; ++j) {
    const int   c  = j * 16 + cc;
    const float bb = f2b[c];
#pragma unroll
    for (int i = 0; i < 4; ++i) {
      const int r = w * 16 + (l >> 4) * 4 + i;
      h2f[r * SH + c] = relu(acc[j][i] + bb);
    }
  }
  __syncthreads();

  {
    const int r  = t >> 2;
    const int c4 = (t & 3) * 4;
    float o4[4] = {0.f, 0.f, 0.f, 0.f};
#pragma unroll 8
    for (int k = 0; k < 64; ++k) {
      const float a = h2f[r * SH + k];
      float4 bw = *(const float4*)&wo[k * OUTD + c4];
      o4[0] += a * bw.x; o4[1] += a * bw.y; o4[2] += a * bw.z; o4[3] += a * bw.w;
    }
#pragma unroll
    for (int j = 0; j < 4; ++j)
      oS[r * 17 + c4 + j] = relu(o4[j] + bo[c4 + j]);
  }
  __syncthreads();

  if (t < 32) {
    const int m = t >> 4;
    const int c = t & 15;
    float s = 0.f;
#pragma unroll
    for (int a = 0; a < 32; ++a) s += oS[(m * 32 + a) * 17 + c];
    out[(blockIdx.x * 2 + m) * OUTD + c] = s;
  }
}

// ===========================================================================
extern "C" void kernel_launch(void* const* d_in, const int* in_sizes, int n_in,
                              void* d_out, int out_size, void* d_ws, size_t ws_size,
                              hipStream_t stream) {
  const float* atom_states = (const float*)d_in[0];
  const int*   edge_src    = (const int*)d_in[1];
  const int*   edge_dst    = (const int*)d_in[2];
  const float* ms0_w = (const float*)d_in[4];
  const float* ms0_b = (const float*)d_in[5];
  const float* ms1_w = (const float*)d_in[6];
  const float* ms1_b = (const float*)d_in[7];
  const float* ms2_w = (const float*)d_in[8];
  const float* ms2_b = (const float*)d_in[9];
  const float* fc1_w = (const float*)d_in[10];
  const float* fc1_b = (const float*)d_in[11];
  const float* fc2_w = (const float*)d_in[12];
  const float* fc2_b = (const float*)d_in[13];
  const float* out_w = (const float*)d_in[14];
  const float* out_b = (const float*)d_in[15];

  // ws layout ~106.6 MiB — R7..R11 ran the use_ds path proving ws >= ~109 MiB.
  char* ws = (char*)d_ws;
  float* new_states = (float*)ws;
  size_t off = (size_t)N_ATOMS * DD * sizeof(float);                    // 32 MiB
  int* cnt     = (int*)(ws + off); off += (size_t)N_ATOMS * 4;          // +512 KiB
  int* bucket  = (int*)(ws + off); off += (size_t)N_ATOMS * BCAP * 4;   // +8 MiB
  int2* ovf    = (int2*)(ws + off); off += (size_t)OVF_CAP * 8;         // +2 MiB
  int* ovf_cnt = (int*)(ws + off); off += 4096;                         // +4 KiB
  unsigned short* whi = (unsigned short*)(ws + off); off += 24576 * 2;  // +48 KiB
  unsigned short* wlo = (unsigned short*)(ws + off); off += 24576 * 2;  // +48 KiB
  float* Yd = (float*)(ws + off); off += (size_t)N_ATOMS * DD * sizeof(float);
  float* Ys = (float*)(ws + off); off += (size_t)N_ATOMS * DD * sizeof(float);

  k0_init_pack<<<141, 256, 0, stream>>>(ms0_w, ms1_w, ms2_w, fc1_w, fc2_w,
                                        cnt, ovf_cnt, whi, wlo);
  k1_scatter_pre<<<6144, 256, 0, stream>>>(atom_states, edge_src, edge_dst,
                                           cnt, bucket, ovf, ovf_cnt,
                                           whi, wlo, ms0_b, Yd, Ys);
  edge_kernel_v8<<<N_ATOMS / 8, 256, 0, stream>>>(
      Yd, Ys, bucket, cnt, whi, wlo, ms1_b, ms2_b, new_states);
  ovf_kernel<<<64, 256, 0, stream>>>(Yd, Ys, ms1_w, ms1_b, ms2_w, ms2_b,
                                     ovf, ovf_cnt, new_states);
  atom_kernel_v2<<<N_ATOMS / 64, 256, 0, stream>>>(
      new_states, whi, wlo, fc1_b, fc2_b, out_w, out_b, (float*)d_out);
}

// Round 13
// 387.938 us; speedup vs baseline: 1.1331x; 1.1331x over previous
//
#include <hip/hip_runtime.h>

// MessagePassingNet on MI355X — Round 13: bucket prep + dense v7 edge kernel.
//   R12 lesson: bucket-shaped edge kernel doubles MFMA/VALU/LDS work (204 µs);
//   but single-atomic-pass prep saved ~44 µs. Hybrid: bucket scatter ->
//   scan(clamped) -> compact to dense dst-sorted (d,src) -> proven v7 edge
//   (130 µs) -> overflow fixup. Dual path on ws_size (C needs ~119 MB,
//   fallback B = R11 hist+scatter pipeline, proven <=114.4 MB).

constexpr int N_ATOMS = 131072;
constexpr int N_EDGES = 1048576;
constexpr int DD      = 64;
constexpr int OUTD    = 16;
constexpr int SH      = 72;     // halfword row stride for hi/lo LDS tiles
constexpr int SY      = 68;     // float row stride for atom_pre staging
constexpr int BCAP    = 16;     // bucket capacity per atom (Poisson(8): ~900 ovf)
constexpr int OVF_CAP = 65536;  // overflow list capacity

typedef __bf16 bf16x8 __attribute__((ext_vector_type(8)));
typedef float  f32x4  __attribute__((ext_vector_type(4)));
typedef unsigned short u16x8 __attribute__((ext_vector_type(8)));

#define DEV_INLINE __device__ __forceinline__

DEV_INLINE float relu(float x) { return x > 0.f ? x : 0.f; }

DEV_INLINE unsigned short bfbits(float x) {
  __bf16 h = (__bf16)x;
  return __builtin_bit_cast(unsigned short, h);
}
DEV_INLINE float bfval(unsigned short u) {
  unsigned int v = ((unsigned int)u) << 16;
  return __builtin_bit_cast(float, v);
}
DEV_INLINE f32x4 mfma16(bf16x8 a, bf16x8 b, f32x4 c) {
  return __builtin_amdgcn_mfma_f32_16x16x32_bf16(a, b, c, 0, 0, 0);
}
DEV_INLINE bf16x8 ldfrag(const unsigned short* p) { return *(const bf16x8*)p; }

DEV_INLINE float4 ldnt(const float4* p) {
  f32x4 v = __builtin_nontemporal_load((const f32x4*)p);
  return make_float4(v.x, v.y, v.z, v.w);
}

DEV_INLINE void mk_frag(float4 a0, float4 a1, bf16x8& fh, bf16x8& fl) {
  const float v[8] = {a0.x, a0.y, a0.z, a0.w, a1.x, a1.y, a1.z, a1.w};
  u16x8 hh, ll;
#pragma unroll
  for (int i = 0; i < 8; ++i) {
    unsigned short h = bfbits(v[i]);
    hh[i] = h;
    ll[i] = bfbits(v[i] - bfval(h));
  }
  fh = __builtin_bit_cast(bf16x8, hh);
  fl = __builtin_bit_cast(bf16x8, ll);
}

// ---- shared atom_pre body: Yd = X*W0d + b0, Ys = X*W0s; LDS-staged stores
DEV_INLINE void atom_pre_body(const float* __restrict__ atom_states,
                              const unsigned short* __restrict__ whi,
                              const unsigned short* __restrict__ wlo,
                              const float* __restrict__ b0,
                              float* __restrict__ Yd, float* __restrict__ Ys,
                              int a0, int t, float* st)
{
  const int l  = t & 63;
  const int w  = t >> 6;
  const int fi = (l >> 4) * 2;
  const int cc = l & 15;
  const int arow = a0 + w * 16 + (l & 15);

  bf16x8 xh[2], xl[2];
  {
    const float4* px = (const float4*)(atom_states + (size_t)arow * DD);
#pragma unroll
    for (int s = 0; s < 2; ++s) {
      float4 x0 = px[s * 8 + fi], x1 = px[s * 8 + fi + 1];
      mk_frag(x0, x1, xh[s], xl[s]);
    }
  }

#pragma unroll
  for (int side = 0; side < 2; ++side) {
    f32x4 acc[4];
#pragma unroll
    for (int j = 0; j < 4; ++j) acc[j] = (f32x4){0.f, 0.f, 0.f, 0.f};
#pragma unroll
    for (int s = 0; s < 2; ++s) {
#pragma unroll
      for (int j = 0; j < 4; ++j) {
        const int fo = side * 4096 + ((j * 2 + s) * 64 + l) * 8;
        bf16x8 bh = ldfrag(whi + fo);
        bf16x8 bl = ldfrag(wlo + fo);
        acc[j] = mfma16(xl[s], bh, acc[j]);
        acc[j] = mfma16(xh[s], bl, acc[j]);
        acc[j] = mfma16(xh[s], bh, acc[j]);
      }
    }
#pragma unroll
    for (int j = 0; j < 4; ++j) {
      const int   c  = j * 16 + cc;
      const float bb = side ? 0.f : b0[c];
#pragma unroll
      for (int i = 0; i < 4; ++i) {
        const int r = (l >> 4) * 4 + i;
        st[r * SY + c] = acc[j][i] + bb;
      }
    }
    {
      float* Y = side ? Ys : Yd;
      const int rr = l >> 2;
      const int c0 = (l & 3) * 16;
      float4* dst = (float4*)(Y + (size_t)(a0 + w * 16 + rr) * DD + c0);
      const float4* src = (const float4*)&st[rr * SY + c0];
#pragma unroll
      for (int f = 0; f < 4; ++f) dst[f] = src[f];
    }
  }
}

// ===========================================================================
// k0: [0,2048) zero new_states | [2048,2176) zero cnt | 2176 zero ovf_cnt |
//     [2177,2189) weight pack.  Sections: 0=W0d 1=W0s 2=W1 3=W2 4=FC1 5=FC2.
// ===========================================================================
__global__ __launch_bounds__(256)
void k0_init_pack(const float* __restrict__ w0, const float* __restrict__ w1,
                  const float* __restrict__ w2, const float* __restrict__ f1,
                  const float* __restrict__ f2,
                  int* __restrict__ cnt, int* __restrict__ ovf_cnt,
                  float* __restrict__ new_states,
                  unsigned short* __restrict__ whi, unsigned short* __restrict__ wlo)
{
  const int t = threadIdx.x, b = blockIdx.x;
  if (b < 2048) {
    float4* ns4 = (float4*)new_states;
    const int n4 = N_ATOMS * DD / 4;
    for (int i = b * 256 + t; i < n4; i += 2048 * 256)
      ns4[i] = make_float4(0.f, 0.f, 0.f, 0.f);
  } else if (b < 2176) {
    ((int4*)cnt)[(b - 2048) * 256 + t] = make_int4(0, 0, 0, 0);
  } else if (b == 2176) {
    if (t == 0) *ovf_cnt = 0;
  } else {
    int tid = (b - 2177) * 256 + t;                  // 0..3071
    int sec = tid >> 9, rel = tid & 511;
    const float* w; int rowoff = 0;
    switch (sec) {
      case 0: w = w0; rowoff = 0;  break;
      case 1: w = w0; rowoff = 64; break;
      case 2: w = w1; break;
      case 3: w = w2; break;
      case 4: w = f1; break;
      default: w = f2; break;
    }
    const int tile = rel >> 6, lane = rel & 63;
    const int j = tile >> 1, s = tile & 1;
    const int n  = j * 16 + (lane & 15);
    const int kb = s * 32 + (lane >> 4) * 8;
    const int out = sec * 4096 + (tile * 64 + lane) * 8;
#pragma unroll
    for (int i = 0; i < 8; ++i) {
      float v = w[(rowoff + kb + i) * 64 + n];
      unsigned short h = bfbits(v);
      whi[out + i] = h;
      wlo[out + i] = bfbits(v - bfval(h));
    }
  }
}

// ===========================================================================
// Path C: k1 = bucket scatter [0,4096) || atom_pre [4096,6144)
// ===========================================================================
__global__ __launch_bounds__(256, 4)
void k1_bucket_pre(const float* __restrict__ atom_states,
                   const int* __restrict__ edge_src,
                   const int* __restrict__ edge_dst,
                   int* __restrict__ cnt, int* __restrict__ bucket,
                   int2* __restrict__ ovf, int* __restrict__ ovf_cnt,
                   const unsigned short* __restrict__ whi,
                   const unsigned short* __restrict__ wlo,
                   const float* __restrict__ b0,
                   float* __restrict__ Yd, float* __restrict__ Ys)
{
  __shared__ float Ystage[4][16 * SY];
  const int t = threadIdx.x, b = blockIdx.x;
  if (b < 4096) {
    int i = b * 256 + t;
    int d = edge_dst[i];
    int pos = atomicAdd(&cnt[d], 1);
    if (pos < BCAP) {
      bucket[d * BCAP + pos] = edge_src[i];
    } else {
      int op = atomicAdd(ovf_cnt, 1);
      if (op < OVF_CAP) ovf[op] = make_int2(d, edge_src[i]);
    }
    return;
  }
  atom_pre_body(atom_states, whi, wlo, b0, Yd, Ys, (b - 4096) * 64, t,
                Ystage[t >> 6]);
}

// ===========================================================================
// Path B: hist only (cnt counts true degree)
// ===========================================================================
__global__ __launch_bounds__(256, 4)
void k1_hist(const int* __restrict__ edge_dst, int* __restrict__ cnt) {
  int i = blockIdx.x * 256 + threadIdx.x;
  atomicAdd(&cnt[edge_dst[i]], 1);
}

// ===========================================================================
// scan chain (clampv = BCAP for C, INT_MAX for B)
// ===========================================================================
__global__ void blocksum_kernel(const int* __restrict__ cnt,
                                int* __restrict__ partial, int clampv) {
  __shared__ int s[256];
  int t = threadIdx.x;
  s[t] = min(cnt[blockIdx.x * 256 + t], clampv);
  __syncthreads();
  for (int off = 128; off > 0; off >>= 1) {
    if (t < off) s[t] += s[t + off];
    __syncthreads();
  }
  if (t == 0) partial[blockIdx.x] = s[0];
}

__global__ void scanwrite_kernel(const int* __restrict__ cnt,
                                 const int* __restrict__ partial,
                                 int* __restrict__ cursor, int clampv) {
  __shared__ int s[256];
  __shared__ int pS[256];
  int t = threadIdx.x, b = blockIdx.x;

  int acc = 0;
  int p0 = partial[t];       if (t < b)       acc += p0;
  int p1 = partial[256 + t]; if (256 + t < b) acc += p1;
  pS[t] = acc;
  __syncthreads();
  for (int off = 128; off > 0; off >>= 1) {
    if (t < off) pS[t] += pS[t + off];
    __syncthreads();
  }
  const int base = pS[0];

  int v = min(cnt[b * 256 + t], clampv);
  s[t] = v;
  __syncthreads();
  for (int off = 1; off < 256; off <<= 1) {
    int x = (t >= off) ? s[t - off] : 0;
    __syncthreads();
    s[t] += x;
    __syncthreads();
  }
  cursor[b * 256 + t] = base + s[t] - v;  // exclusive prefix of clamped cnt
}

// ===========================================================================
// Path C: compact buckets -> dense dst-sorted (d, src). 32 atoms/block,
// 512 jobs (atom, slot), 2 per thread. No atomics, dense writes.
// ===========================================================================
__global__ __launch_bounds__(256)
void compact_kernel(const int* __restrict__ cnt, const int* __restrict__ cursor,
                    const int* __restrict__ bucket, int2* __restrict__ ds_sorted) {
  const int t = threadIdx.x, b = blockIdx.x;
#pragma unroll
  for (int h = 0; h < 2; ++h) {
    const int j = h * 256 + t;            // 0..511
    const int a = b * 32 + (j >> 4);
    const int slot = j & 15;
    if (slot < min(cnt[a], BCAP))
      ds_sorted[cursor[a] + slot] = make_int2(a, bucket[a * BCAP + slot]);
  }
}

// ===========================================================================
// Path B: scatter -> ds_sorted directly [0,4096) || atom_pre [4096,6144)
// ===========================================================================
__global__ __launch_bounds__(256, 4)
void k2_scatter_pre(const float* __restrict__ atom_states,
                    const int* __restrict__ edge_src,
                    const int* __restrict__ edge_dst,
                    int* __restrict__ cursor, int2* __restrict__ ds_sorted,
                    const unsigned short* __restrict__ whi,
                    const unsigned short* __restrict__ wlo,
                    const float* __restrict__ b0,
                    float* __restrict__ Yd, float* __restrict__ Ys)
{
  __shared__ float Ystage[4][16 * SY];
  const int t = threadIdx.x, b = blockIdx.x;
  if (b < 4096) {
    int i = b * 256 + t;
    int d = edge_dst[i];
    int pos = atomicAdd(&cursor[d], 1);
    ds_sorted[pos] = make_int2(d, edge_src[i]);
    return;
  }
  atom_pre_body(atom_states, whi, wlo, b0, Yd, Ys, (b - 4096) * 64, t,
                Ystage[t >> 6]);
}

// ===========================================================================
// edge_kernel_v7c: wave-autonomous, 32 edges/wave, register A-fragments,
// non-temporal Ys loads, per-wave segmented reduction. total = N_EDGES - ovf.
// ===========================================================================
__global__ __launch_bounds__(256, 4)
void edge_kernel_v7c(const float* __restrict__ Yd,
                     const float* __restrict__ Ys,
                     const int2* __restrict__ ds_sorted,
                     const int* __restrict__ ovf_cnt,
                     const unsigned short* __restrict__ whi,
                     const unsigned short* __restrict__ wlo,
                     const float* __restrict__ b1,
                     const float* __restrict__ b2,
                     float* __restrict__ new_states)
{
  __shared__ __align__(16) unsigned short H2[4][2 * 32 * SH];

  const int t = threadIdx.x;
  const int w = t >> 6;
  const int l = t & 63;
  const int e0 = blockIdx.x * 128 + w * 32;

  const int total = N_EDGES - min(*ovf_cnt, OVF_CAP);
  const int n = min(max(total - e0, 0), 32);
  if (n <= 0) return;                    // wave-autonomous: safe to exit

  unsigned short* h2 = H2[w];
  float* msg = (float*)H2[w];

  int d = 0, s = 0;
  if (l < 32 && e0 + l < total) {
    int2 ds = ds_sorted[e0 + l];
    d = ds.x; s = ds.y;
  }

  const int m  = l & 15;
  const int fi = (l >> 4) * 2;
  const int cc = l & 15;

  bf16x8 a1h[2][2], a1l[2][2];
#pragma unroll
  for (int tile = 0; tile < 2; ++tile) {
    const int dm = __shfl(d, tile * 16 + m);
    const int sm = __shfl(s, tile * 16 + m);
    const float4* pd = (const float4*)(Yd + (size_t)dm * DD);
    const float4* ps = (const float4*)(Ys + (size_t)sm * DD);
#pragma unroll
    for (int s2 = 0; s2 < 2; ++s2) {
      float4 x0 = pd[s2 * 8 + fi], x1 = pd[s2 * 8 + fi + 1];
      float4 y0 = ldnt(ps + s2 * 8 + fi), y1 = ldnt(ps + s2 * 8 + fi + 1);
      float4 r0 = make_float4(relu(x0.x + y0.x), relu(x0.y + y0.y),
                              relu(x0.z + y0.z), relu(x0.w + y0.w));
      float4 r1 = make_float4(relu(x1.x + y1.x), relu(x1.y + y1.y),
                              relu(x1.z + y1.z), relu(x1.w + y1.w));
      mk_frag(r0, r1, a1h[tile][s2], a1l[tile][s2]);
    }
  }

  f32x4 acc[2][4];

#pragma unroll
  for (int tile = 0; tile < 2; ++tile)
#pragma unroll
    for (int j = 0; j < 4; ++j) acc[tile][j] = (f32x4){0.f, 0.f, 0.f, 0.f};
#pragma unroll
  for (int s2 = 0; s2 < 2; ++s2) {
#pragma unroll
    for (int j = 0; j < 4; ++j) {
      const int fo = 2 * 4096 + ((j * 2 + s2) * 64 + l) * 8;
      bf16x8 bh = ldfrag(whi + fo);
      bf16x8 bl = ldfrag(wlo + fo);
#pragma unroll
      for (int tile = 0; tile < 2; ++tile) {
        acc[tile][j] = mfma16(a1l[tile][s2], bh, acc[tile][j]);
        acc[tile][j] = mfma16(a1h[tile][s2], bl, acc[tile][j]);
        acc[tile][j] = mfma16(a1h[tile][s2], bh, acc[tile][j]);
      }
    }
  }
#pragma unroll
  for (int tile = 0; tile < 2; ++tile) {
#pragma unroll
    for (int j = 0; j < 4; ++j) {
      const int   c  = j * 16 + cc;
      const float bb = b1[c];
#pragma unroll
      for (int i = 0; i < 4; ++i) {
        const int r = tile * 16 + (l >> 4) * 4 + i;
        float v = relu(acc[tile][j][i] + bb);
        unsigned short hi = bfbits(v);
        h2[r * SH + c] = hi;
        h2[32 * SH + r * SH + c] = bfbits(v - bfval(hi));
      }
    }
  }

#pragma unroll
  for (int tile = 0; tile < 2; ++tile)
#pragma unroll
    for (int j = 0; j < 4; ++j) acc[tile][j] = (f32x4){0.f, 0.f, 0.f, 0.f};
  const int kq = (l >> 4) * 8;
#pragma unroll
  for (int s2 = 0; s2 < 2; ++s2) {
    bf16x8 ah[2], al[2];
#pragma unroll
    for (int tile = 0; tile < 2; ++tile) {
      const int mrow = tile * 16 + m;
      ah[tile] = ldfrag(&h2[mrow * SH + s2 * 32 + kq]);
      al[tile] = ldfrag(&h2[32 * SH + mrow * SH + s2 * 32 + kq]);
    }
#pragma unroll
    for (int j = 0; j < 4; ++j) {
      const int fo = 3 * 4096 + ((j * 2 + s2) * 64 + l) * 8;
      bf16x8 bh = ldfrag(whi + fo);
      bf16x8 bl = ldfrag(wlo + fo);
#pragma unroll
      for (int tile = 0; tile < 2; ++tile) {
        acc[tile][j] = mfma16(al[tile], bh, acc[tile][j]);
        acc[tile][j] = mfma16(ah[tile], bl, acc[tile][j]);
        acc[tile][j] = mfma16(ah[tile], bh, acc[tile][j]);
      }
    }
  }
#pragma unroll
  for (int tile = 0; tile < 2; ++tile) {
#pragma unroll
    for (int j = 0; j < 4; ++j) {
      const int   c  = j * 16 + cc;
      const float bb = b2[c];
#pragma unroll
      for (int i = 0; i < 4; ++i) {
        const int r = tile * 16 + (l >> 4) * 4 + i;
        msg[r * SH + c] = relu(acc[tile][j][i] + bb);
      }
    }
  }

  // ---- segmented reduction over rows [0, n)
  if (n == 32) {
    int   cur   = __builtin_amdgcn_readlane(d, 0);
    float run   = 0.f;
    bool  first = true;
#pragma unroll
    for (int r = 0; r < 32; ++r) {
      float v  = msg[r * SH + l];
      int   dr = __builtin_amdgcn_readlane(d, r);
      if (r > 0 && dr != cur) {
        float* p = new_states + (size_t)cur * DD + l;
        if (first) atomicAdd(p, run);
        else       *p = run;
        first = false;
        run = 0.f;
        cur = dr;
      }
      run += v;
    }
    atomicAdd(new_states + (size_t)cur * DD + l, run);
  } else {
    int   cur   = __builtin_amdgcn_readlane(d, 0);
    float run   = 0.f;
    bool  first = true;
    for (int r = 0; r < n; ++r) {
      float v  = msg[r * SH + l];
      int   dr = __builtin_amdgcn_readlane(d, r);
      if (r > 0 && dr != cur) {
        float* p = new_states + (size_t)cur * DD + l;
        if (first) atomicAdd(p, run);
        else       *p = run;
        first = false;
        run = 0.f;
        cur = dr;
      }
      run += v;
    }
    atomicAdd(new_states + (size_t)cur * DD + l, run);
  }
}

// ===========================================================================
// ovf_kernel: fp32 message MLP for overflow edges, one wave/edge, atomicAdd.
// ===========================================================================
__global__ __launch_bounds__(256, 4)
void ovf_kernel(const float* __restrict__ Yd, const float* __restrict__ Ys,
                const float* __restrict__ w1, const float* __restrict__ b1,
                const float* __restrict__ w2, const float* __restrict__ b2,
                const int2* __restrict__ ovf, const int* __restrict__ ovf_cnt,
                float* __restrict__ new_states)
{
  __shared__ float hb[4][64];
  const int t = threadIdx.x;
  const int w = t >> 6;
  const int l = t & 63;
  const int wid = blockIdx.x * 4 + w;
  const int NW  = gridDim.x * 4;

  const int n = min(*ovf_cnt, OVF_CAP);
  for (int e = wid; e < n; e += NW) {
    int2 ds = ovf[e];
    float h1 = relu(Yd[(size_t)ds.x * DD + l] + Ys[(size_t)ds.y * DD + l]);
    hb[w][l] = h1;
    float acc = 0.f;
#pragma unroll 8
    for (int k = 0; k < 64; ++k) acc += hb[w][k] * w1[k * 64 + l];
    float h2 = relu(acc + b1[l]);
    hb[w][l] = h2;
    acc = 0.f;
#pragma unroll 8
    for (int k = 0; k < 64; ++k) acc += hb[w][k] * w2[k * 64 + l];
    atomicAdd(&new_states[(size_t)ds.x * DD + l], relu(acc + b2[l]));
  }
}

// ===========================================================================
// atom_kernel_v2 (proven): readout MFMA + fp32 out + mol sum.
// ===========================================================================
__global__ __launch_bounds__(256, 4)
void atom_kernel_v2(const float* __restrict__ ns,
                    const unsigned short* __restrict__ whi,
                    const unsigned short* __restrict__ wlo,
                    const float* __restrict__ f1b,
                    const float* __restrict__ f2b,
                    const float* __restrict__ wo,
                    const float* __restrict__ bo,
                    float* __restrict__ out)
{
  __shared__ __align__(16) unsigned short Xb[2 * 64 * SH];
  __shared__ __align__(16) unsigned short Hb[2 * 64 * SH];
  unsigned short* Xh = Xb;
  unsigned short* Xl = Xb + 64 * SH;
  unsigned short* Hh = Hb;
  unsigned short* Hl = Hb + 64 * SH;
  float* h2f = (float*)Xb;
  float* oS  = (float*)Hb;

  const int t  = threadIdx.x;
  const int a0 = blockIdx.x * 64;

  {
    const int r  = t >> 2;
    const int k0 = (t & 3) * 16;
    const float4* s4 = (const float4*)(ns + (size_t)(a0 + r) * DD + k0);
#pragma unroll
    for (int f = 0; f < 4; ++f) {
      float4 v = s4[f];
      ushort4 h, lo;
      h.x = bfbits(v.x); lo.x = bfbits(v.x - bfval(h.x));
      h.y = bfbits(v.y); lo.y = bfbits(v.y - bfval(h.y));
      h.z = bfbits(v.z); lo.z = bfbits(v.z - bfval(h.z));
      h.w = bfbits(v.w); lo.w = bfbits(v.w - bfval(h.w));
      *(ushort4*)&Xh[r * SH + k0 + f * 4] = h;
      *(ushort4*)&Xl[r * SH + k0 + f * 4] = lo;
    }
  }

  const int l    = t & 63;
  const int w    = t >> 6;
  const int mrow = w * 16 + (l & 15);
  const int kq   = (l >> 4) * 8;
  const int cc   = l & 15;

  f32x4 acc[4];

#pragma unroll
  for (int j = 0; j < 4; ++j) acc[j] = (f32x4){0.f, 0.f, 0.f, 0.f};
#pragma unroll
  for (int s = 0; s < 2; ++s) {
    bf16x8 ah = ldfrag(&Xh[mrow * SH + s * 32 + kq]);
    bf16x8 al = ldfrag(&Xl[mrow * SH + s * 32 + kq]);
#pragma unroll
    for (int j = 0; j < 4; ++j) {
      const int fo = 4 * 4096 + ((j * 2 + s) * 64 + l) * 8;
      bf16x8 bh = ldfrag(whi + fo);
      bf16x8 bl = ldfrag(wlo + fo);
      acc[j] = mfma16(al, bh, acc[j]);
      acc[j] = mfma16(ah, bl, acc[j]);
      acc[j] = mfma16(ah, bh, acc[j]);
    }
  }
#pragma unroll
  for (int j = 0; j < 4; ++j) {
    const int   c  = j * 16 + cc;
    const float bb = f1b[c];
#pragma unroll
    for (int i = 0; i < 4; ++i) {
      const int r = w * 16 + (l >> 4) * 4 + i;
      float v = relu(acc[j][i] + bb);
      unsigned short hi = bfbits(v);
      Hh[r * SH + c] = hi;
      Hl[r * SH + c] = bfbits(v - bfval(hi));
    }
  }
  __syncthreads();

#pragma unroll
  for (int j = 0; j < 4; ++j) acc[j] = (f32x4){0.f, 0.f, 0.f, 0.f};
#pragma unroll
  for (int s = 0; s < 2; ++s) {
    bf16x8 ah = ldfrag(&Hh[mrow * SH + s * 32 + kq]);
    bf16x8 al = ldfrag(&Hl[mrow * SH + s * 32 + kq]);
#pragma unroll
    for (int j = 0; j < 4; ++j) {
      const int fo = 5 * 4096 + ((j * 2 + s) * 64 + l) * 8;
      bf16x8 bh = ldfrag(whi + fo);
      bf16x8 bl = ldfrag(wlo + fo);
      acc[j] = mfma16(al, bh, acc[j]);
      acc[j] = mfma16(ah, bl, acc[j]);
      acc[j] = mfma16(ah, bh, acc[j]);
    }
  }
#pragma unroll
  for (int j = 0; j < 4; ++j) {
    const int   c  = j * 16 + cc;
    const float bb = f2b[c];
#pragma unroll
    for (int i = 0; i < 4; ++i) {
      const int r = w * 16 + (l >> 4) * 4 + i;
      h2f[r * SH + c] = relu(acc[j][i] + bb);
    }
  }
  __syncthreads();

  {
    const int r  = t >> 2;
    const int c4 = (t & 3) * 4;
    float o4[4] = {0.f, 0.f, 0.f, 0.f};
#pragma unroll 8
    for (int k = 0; k < 64; ++k) {
      const float a = h2f[r * SH + k];
      float4 bw = *(const float4*)&wo[k * OUTD + c4];
      o4[0] += a * bw.x; o4[1] += a * bw.y; o4[2] += a * bw.z; o4[3] += a * bw.w;
    }
#pragma unroll
    for (int j = 0; j < 4; ++j)
      oS[r * 17 + c4 + j] = relu(o4[j] + bo[c4 + j]);
  }
  __syncthreads();

  if (t < 32) {
    const int m = t >> 4;
    const int c = t & 15;
    float s = 0.f;
#pragma unroll
    for (int a = 0; a < 32; ++a) s += oS[(m * 32 + a) * 17 + c];
    out[(blockIdx.x * 2 + m) * OUTD + c] = s;
  }
}

// ===========================================================================
extern "C" void kernel_launch(void* const* d_in, const int* in_sizes, int n_in,
                              void* d_out, int out_size, void* d_ws, size_t ws_size,
                              hipStream_t stream) {
  const float* atom_states = (const float*)d_in[0];
  const int*   edge_src    = (const int*)d_in[1];
  const int*   edge_dst    = (const int*)d_in[2];
  const float* ms0_w = (const float*)d_in[4];
  const float* ms0_b = (const float*)d_in[5];
  const float* ms1_w = (const float*)d_in[6];
  const float* ms1_b = (const float*)d_in[7];
  const float* ms2_w = (const float*)d_in[8];
  const float* ms2_b = (const float*)d_in[9];
  const float* fc1_w = (const float*)d_in[10];
  const float* fc1_b = (const float*)d_in[11];
  const float* fc2_w = (const float*)d_in[12];
  const float* fc2_b = (const float*)d_in[13];
  const float* out_w = (const float*)d_in[14];
  const float* out_b = (const float*)d_in[15];

  char* ws = (char*)d_ws;
  float* new_states = (float*)ws;
  size_t off = (size_t)N_ATOMS * DD * sizeof(float);                    // 32 MiB
  int* cnt     = (int*)(ws + off); off += (size_t)N_ATOMS * 4;          // +512 KiB
  int* cursor  = (int*)(ws + off); off += (size_t)N_ATOMS * 4;          // +512 KiB
  int* partial = (int*)(ws + off); off += 4096;
  int* ovf_cnt = (int*)(ws + off); off += 4096;
  int2* ovf    = (int2*)(ws + off); off += (size_t)OVF_CAP * 8;         // +512 KiB
  unsigned short* whi = (unsigned short*)(ws + off); off += 24576 * 2;
  unsigned short* wlo = (unsigned short*)(ws + off); off += 24576 * 2;
  float* Yd = (float*)(ws + off); off += (size_t)N_ATOMS * DD * sizeof(float);
  float* Ys = (float*)(ws + off); off += (size_t)N_ATOMS * DD * sizeof(float);
  int2* ds_sorted = (int2*)(ws + off); off += (size_t)N_EDGES * 8;      // +8 MiB
  const size_t needB = off;                                             // ~105.6 MiB
  int* bucket = (int*)(ws + off); off += (size_t)N_ATOMS * BCAP * 4;    // +8 MiB
  const size_t needC = off;                                             // ~113.6 MiB

  const int useC = (ws_size >= needC) ? 1 : 0;   // constant across calls

  k0_init_pack<<<2189, 256, 0, stream>>>(ms0_w, ms1_w, ms2_w, fc1_w, fc2_w,
                                         cnt, ovf_cnt, new_states, whi, wlo);

  if (useC) {
    k1_bucket_pre<<<6144, 256, 0, stream>>>(atom_states, edge_src, edge_dst,
                                            cnt, bucket, ovf, ovf_cnt,
                                            whi, wlo, ms0_b, Yd, Ys);
    blocksum_kernel<<<512, 256, 0, stream>>>(cnt, partial, BCAP);
    scanwrite_kernel<<<512, 256, 0, stream>>>(cnt, partial, cursor, BCAP);
    compact_kernel<<<N_ATOMS / 32, 256, 0, stream>>>(cnt, cursor, bucket, ds_sorted);
  } else {
    k1_hist<<<4096, 256, 0, stream>>>(edge_dst, cnt);
    blocksum_kernel<<<512, 256, 0, stream>>>(cnt, partial, 0x7fffffff);
    scanwrite_kernel<<<512, 256, 0, stream>>>(cnt, partial, cursor, 0x7fffffff);
    k2_scatter_pre<<<6144, 256, 0, stream>>>(atom_states, edge_src, edge_dst,
                                             cursor, ds_sorted,
                                             whi, wlo, ms0_b, Yd, Ys);
  }

  edge_kernel_v7c<<<N_EDGES / 128, 256, 0, stream>>>(
      Yd, Ys, ds_sorted, ovf_cnt, whi, wlo, ms1_b, ms2_b, new_states);

  if (useC) {
    ovf_kernel<<<64, 256, 0, stream>>>(Yd, Ys, ms1_w, ms1_b, ms2_w, ms2_b,
                                       ovf, ovf_cnt, new_states);
  }

  atom_kernel_v2<<<N_ATOMS / 64, 256, 0, stream>>>(
      new_states, whi, wlo, fc1_b, fc2_b, out_w, out_b, (float*)d_out);
}